// Round 14
// baseline (323.603 us; speedup 1.0000x reference)
//
#include <hip/hip_runtime.h>
#include <math.h>

#define C_WAY 10
#define K_SHOT 5
#define T_LEN 16
#define D_DIM 1024
#define NW 3
#define SEG_L 8

static inline int cdiv(int a, int b) { return (a + b - 1) / b; }

__device__ __forceinline__ float wsum(float v) {
#pragma unroll
    for (int o = 32; o; o >>= 1) v += __shfl_xor(v, o);
    return v;
}
__device__ __forceinline__ float wmax(float v) {
#pragma unroll
    for (int o = 32; o; o >>= 1) v = fmaxf(v, __shfl_xor(v, o));
    return v;
}
__device__ __forceinline__ float wsum8(float v) {
#pragma unroll
    for (int o = 4; o; o >>= 1) v += __shfl_xor(v, o);
    return v;
}
__device__ __forceinline__ float wmax8(float v) {
#pragma unroll
    for (int o = 4; o; o >>= 1) v = fmaxf(v, __shfl_xor(v, o));
    return v;
}

// proto[c,t,:] = mean_k support[(c*K+k), t, :]; pn_inv = 1/max(||proto row||, eps)
__global__ __launch_bounds__(256) void k_proto(const float* __restrict__ sup,
                                               float* __restrict__ proto,
                                               float* __restrict__ pn_inv) {
    int bid = blockIdx.x;  // c*16 + t
    int c = bid >> 4, t = bid & 15;
    int tid = threadIdx.x;
    float4 acc = {0.f, 0.f, 0.f, 0.f};
#pragma unroll
    for (int k = 0; k < K_SHOT; ++k) {
        float4 v = *(const float4*)&sup[(((size_t)(c * K_SHOT + k)) * T_LEN + t) * D_DIM + tid * 4];
        acc.x += v.x; acc.y += v.y; acc.z += v.z; acc.w += v.w;
    }
    const float s = 1.0f / (float)K_SHOT;
    acc.x *= s; acc.y *= s; acc.z *= s; acc.w *= s;
    *(float4*)&proto[(size_t)bid * D_DIM + tid * 4] = acc;
    float sq = acc.x * acc.x + acc.y * acc.y + acc.z * acc.z + acc.w * acc.w;
    __shared__ float red[4];
    sq = wsum(sq);
    if ((tid & 63) == 0) red[tid >> 6] = sq;
    __syncthreads();
    if (tid == 0) {
        float tot = red[0] + red[1] + red[2] + red[3];
        pn_inv[bid] = 1.0f / fmaxf(sqrtf(tot), 1e-12f);
    }
}

// inv[r] = 1/max(||X[r,:]||, eps); one wave per row
__global__ __launch_bounds__(256) void k_rowinv(const float* __restrict__ X,
                                                float* __restrict__ inv, int nrows) {
    int r = blockIdx.x * 4 + (threadIdx.x >> 6);
    int lane = threadIdx.x & 63;
    if (r >= nrows) return;
    float sq = 0.f;
#pragma unroll
    for (int i = 0; i < 4; ++i) {
        float4 v = *(const float4*)&X[(size_t)r * D_DIM + (i * 64 + lane) * 4];
        sq += v.x * v.x + v.y * v.y + v.z * v.z + v.w * v.w;
    }
    sq = wsum(sq);
    if (lane == 0) inv[r] = 1.0f / fmaxf(sqrtf(sq), 1e-12f);
}

// qcond[(q*3+v), :] = normalize(mean_l query[q, v*4+l, :])
__global__ __launch_bounds__(256) void k_qcond(const float* __restrict__ query,
                                               float* __restrict__ qcond) {
    int bid = blockIdx.x;  // q*3+v
    int q = bid / 3, v = bid % 3;
    int tid = threadIdx.x;
    float4 acc = {0.f, 0.f, 0.f, 0.f};
#pragma unroll
    for (int l = 0; l < SEG_L; ++l) {
        float4 x = *(const float4*)&query[((size_t)q * T_LEN + v * 4 + l) * D_DIM + tid * 4];
        acc.x += x.x; acc.y += x.y; acc.z += x.z; acc.w += x.w;
    }
    acc.x *= 0.125f; acc.y *= 0.125f; acc.z *= 0.125f; acc.w *= 0.125f;
    float sq = acc.x * acc.x + acc.y * acc.y + acc.z * acc.z + acc.w * acc.w;
    __shared__ float red[4];
    sq = wsum(sq);
    if ((tid & 63) == 0) red[tid >> 6] = sq;
    __syncthreads();
    float tot = red[0] + red[1] + red[2] + red[3];
    float scl = 1.0f / fmaxf(sqrtf(tot), 1e-12f);
    acc.x *= scl; acc.y *= scl; acc.z *= scl; acc.w *= scl;
    *(float4*)&qcond[(size_t)bid * D_DIM + tid * 4] = acc;
}

// scond[(c*3+w), :] = normalize(mean_{k,l} support[(c*K+k), w*4+l, :])
__global__ __launch_bounds__(256) void k_supcond(const float* __restrict__ sup,
                                                 float* __restrict__ scond) {
    int bid = blockIdx.x;  // c*3+w
    int c = bid / 3, w = bid % 3;
    int tid = threadIdx.x;
    float4 acc = {0.f, 0.f, 0.f, 0.f};
    for (int k = 0; k < K_SHOT; ++k)
#pragma unroll
        for (int l = 0; l < SEG_L; ++l) {
            float4 x = *(const float4*)&sup[(((size_t)(c * K_SHOT + k)) * T_LEN + w * 4 + l) * D_DIM + tid * 4];
            acc.x += x.x; acc.y += x.y; acc.z += x.z; acc.w += x.w;
        }
    const float s = 1.0f / 40.0f;
    acc.x *= s; acc.y *= s; acc.z *= s; acc.w *= s;
    float sq = acc.x * acc.x + acc.y * acc.y + acc.z * acc.z + acc.w * acc.w;
    __shared__ float red[4];
    sq = wsum(sq);
    if ((tid & 63) == 0) red[tid >> 6] = sq;
    __syncthreads();
    float tot = red[0] + red[1] + red[2] + red[3];
    float scl = 1.0f / fmaxf(sqrtf(tot), 1e-12f);
    acc.x *= scl; acc.y *= scl; acc.z *= scl; acc.w *= scl;
    *(float4*)&scond[(size_t)bid * D_DIM + tid * 4] = acc;
}

__global__ __launch_bounds__(256) void k_rowmaps(int* __restrict__ map_cls,
                                                 int* __restrict__ map_qseg, int Q) {
    int i = blockIdx.x * 256 + threadIdx.x;
    if (i < C_WAY * NW * 40) {
        int c = i / 120, rem = i % 120, w = rem / 40, n = rem % 40, k = n >> 3, l = n & 7;
        map_cls[i] = (c * K_SHOT + k) * T_LEN + w * 4 + l;
    }
    if (i < Q * NW * SEG_L) {
        int q = i / 24, rem = i % 24, v = rem / 8, l = rem & 7;
        map_qseg[i] = q * T_LEN + v * 4 + l;
    }
}

// C[b][m,n] = sum_k A[rowA(b,m), k] * B[rowB(b,n), k]   (A,B row-major, K inner)
__global__ __launch_bounds__(256) void gemm_bt(const float* __restrict__ A,
                                               const float* __restrict__ B,
                                               float* __restrict__ C,
                                               int M, int N, int K,
                                               const int* __restrict__ mapA, int mapAs,
                                               const int* __restrict__ mapB, int mapBs,
                                               long cstride) {
    __shared__ __align__(16) float As[16][68];
    __shared__ __align__(16) float Bs[16][68];
    int b = blockIdx.z;
    const int* mA = mapA ? mapA + (size_t)b * mapAs : nullptr;
    const int* mB = mapB ? mapB + (size_t)b * mapBs : nullptr;
    float* Cb = C + (size_t)b * cstride;
    int m0 = blockIdx.x * 64, n0 = blockIdx.y * 64;
    int tid = threadIdx.x;
    int tx = tid & 15, ty = tid >> 4;
    int lr = tid >> 2;
    int lk = (tid & 3) * 4;
    long arow = -1, brow = -1;
    if (m0 + lr < M) arow = mA ? mA[m0 + lr] : (m0 + lr);
    if (n0 + lr < N) brow = mB ? mB[n0 + lr] : (n0 + lr);
    float acc[4][4] = {};
    for (int k0 = 0; k0 < K; k0 += 16) {
        float4 av = {0.f, 0.f, 0.f, 0.f}, bv = {0.f, 0.f, 0.f, 0.f};
        if (arow >= 0) av = *(const float4*)&A[(size_t)arow * K + k0 + lk];
        if (brow >= 0) bv = *(const float4*)&B[(size_t)brow * K + k0 + lk];
        __syncthreads();
        As[lk + 0][lr] = av.x; As[lk + 1][lr] = av.y; As[lk + 2][lr] = av.z; As[lk + 3][lr] = av.w;
        Bs[lk + 0][lr] = bv.x; Bs[lk + 1][lr] = bv.y; Bs[lk + 2][lr] = bv.z; Bs[lk + 3][lr] = bv.w;
        __syncthreads();
#pragma unroll
        for (int k = 0; k < 16; ++k) {
            float4 a4 = *(const float4*)&As[k][ty * 4];
            float4 b4 = *(const float4*)&Bs[k][tx * 4];
            float a[4] = {a4.x, a4.y, a4.z, a4.w};
            float bb[4] = {b4.x, b4.y, b4.z, b4.w};
#pragma unroll
            for (int i = 0; i < 4; ++i)
#pragma unroll
                for (int j = 0; j < 4; ++j) acc[i][j] = fmaf(a[i], bb[j], acc[i][j]);
        }
    }
#pragma unroll
    for (int i = 0; i < 4; ++i) {
        int m = m0 + ty * 4 + i;
        if (m >= M) break;
#pragma unroll
        for (int j = 0; j < 4; ++j) {
            int n = n0 + tx * 4 + j;
            if (n < N) Cb[(size_t)m * N + n] = acc[i][j];
        }
    }
}

// Gq[(q*3+v)][n*8+m] = dot(q_seg[q,v,n,:], q_seg[q,v,m,:]); one wave per block
__global__ __launch_bounds__(64) void k_gq(const float* __restrict__ query,
                                           float* __restrict__ Gq) {
    __shared__ __align__(16) float s[8 * 1028];
    int bid = blockIdx.x;  // q*3+v
    int q = bid / 3, v = bid % 3;
    int lane = threadIdx.x;
#pragma unroll
    for (int i = 0; i < 32; ++i) {
        int f4 = i * 64 + lane;  // 0..2047 float4 index
        int row = f4 >> 8, c4 = f4 & 255;
        float4 val = *(const float4*)&query[((size_t)q * T_LEN + v * 4 + row) * D_DIM + c4 * 4];
        *(float4*)&s[row * 1028 + c4 * 4] = val;
    }
    __syncthreads();
    int n = lane >> 3, m = lane & 7;
    const float* ra = &s[n * 1028];
    const float* rb = &s[m * 1028];
    float acc = 0.f;
    for (int t = 0; t < 256; ++t) {
        float4 a = *(const float4*)&ra[t * 4];
        float4 b = *(const float4*)&rb[t * 4];
        acc = fmaf(a.x, b.x, acc); acc = fmaf(a.y, b.y, acc);
        acc = fmaf(a.z, b.z, acc); acc = fmaf(a.w, b.w, acc);
    }
    Gq[(size_t)bid * 64 + lane] = acc;
}

// global_score[q, c] from SIM (raw dots) with row/col scales; block per q
__global__ __launch_bounds__(256) void k_greduce(const float* __restrict__ SIM,
                                                 const float* __restrict__ qrow_inv,
                                                 const float* __restrict__ pn_inv,
                                                 float* __restrict__ gscore) {
    __shared__ float d[16 * 160];
    __shared__ float rmin[160], cmin[160];
    int q = blockIdx.x, tid = threadIdx.x;
#pragma unroll
    for (int i = 0; i < 10; ++i) {
        int idx = tid + i * 256;  // 0..2559
        int t = idx / 160, col = idx % 160;
        float v = SIM[((size_t)(q * 16 + t)) * 160 + col] * qrow_inv[q * 16 + t] * pn_inv[col];
        d[idx] = 1.0f - v;
    }
    __syncthreads();
    if (tid < 160) {
        int c = tid / 16, t = tid % 16;
        float mn = 3.4e38f;
#pragma unroll
        for (int s2 = 0; s2 < 16; ++s2) mn = fminf(mn, d[t * 160 + c * 16 + s2]);
        rmin[tid] = mn;
        int s = t;
        mn = 3.4e38f;
#pragma unroll
        for (int t2 = 0; t2 < 16; ++t2) mn = fminf(mn, d[t2 * 160 + c * 16 + s]);
        cmin[tid] = mn;
    }
    __syncthreads();
    if (tid < 10) {
        float sum = 0.f;
#pragma unroll
        for (int t = 0; t < 16; ++t) sum += rmin[tid * 16 + t] + cmin[tid * 16 + t];
        gscore[q * 10 + tid] = -sum;
    }
}

// final fused scoring: one wave per (q,c)
__global__ __launch_bounds__(64) void k_final(const float* __restrict__ S_raw,
                                              const float* __restrict__ Q_raw,
                                              const float* __restrict__ G_sup,
                                              const float* __restrict__ G_q,
                                              const float* __restrict__ gscore,
                                              const float* __restrict__ fusion,
                                              float* __restrict__ out) {
    int bid = blockIdx.x;  // q*10 + c
    int q = bid / 10, c = bid % 10;
    int lane = threadIdx.x;
    const float inv_sqrt_d = 0.03125f;  // 1/sqrt(1024)
    float b1s = -3.4e38f, b2s = -3.4e38f;
    float b1q = -3.4e38f, b2q = -3.4e38f;
    for (int vw = 0; vw < 9; ++vw) {
        int v = vw / 3, w = vw % 3;
        // ---- s2q: softmax over 40 support tokens ----
        bool act = lane < 40;
        float raw = act ? S_raw[((size_t)(q * 3 + v)) * 1200 + (c * 3 + w) * 40 + lane] : 0.f;
        float x = act ? raw * inv_sqrt_d : -3.4e38f;
        float mx = wmax(x);
        float e = act ? __expf(x - mx) : 0.f;
        float ssum = wsum(e);
        float attn = act ? e / ssum : 0.f;
        float dotqp = wsum(attn * raw);
        float inner = 0.f;
        const float* G = &G_sup[(size_t)(c * 3 + w) * 1600];
        for (int m = 0; m < 40; ++m) {
            float am = __shfl(attn, m);
            float g = act ? G[m * 40 + lane] : 0.f;
            inner = fmaf(am, g, inner);
        }
        float nrm2 = wsum(attn * inner);
        float sc_s2q = dotqp / fmaxf(sqrtf(fmaxf(nrm2, 0.f)), 1e-12f);
        // ---- q2s: softmax over 8 query tokens (lanes 0..7, group-of-8 reduces) ----
        bool act8 = lane < 8;
        float qraw = act8 ? Q_raw[((size_t)((q * 3 + v) * 8 + lane)) * 30 + (c * 3 + w)] : 0.f;
        float x8 = act8 ? qraw * inv_sqrt_d : -3.4e38f;
        float mx8 = wmax8(x8);
        float e8 = act8 ? __expf(x8 - mx8) : 0.f;
        float s8 = wsum8(e8);
        float attn8 = act8 ? e8 / s8 : 0.f;
        float dotq2 = wsum8(attn8 * qraw);
        float inner8 = 0.f;
        const float* Gqp = &G_q[(size_t)(q * 3 + v) * 64];
        for (int m = 0; m < 8; ++m) {
            float am = __shfl(attn8, m);
            float g = act8 ? Gqp[m * 8 + lane] : 0.f;
            inner8 = fmaf(am, g, inner8);
        }
        float nrm28 = wsum8(attn8 * inner8);
        float sc_q2s = dotq2 / fmaxf(sqrtf(fmaxf(nrm28, 0.f)), 1e-12f);
        sc_q2s = __shfl(sc_q2s, 0);
        if (sc_s2q > b1s) { b2s = b1s; b1s = sc_s2q; } else if (sc_s2q > b2s) b2s = sc_s2q;
        if (sc_q2s > b1q) { b2q = b1q; b1q = sc_q2s; } else if (sc_q2s > b2q) b2q = sc_q2s;
    }
    if (lane == 0) {
        float seg = 0.5f * (0.5f * (b1s + b2s) + 0.5f * (b1q + b2q));
        float l0 = fusion[0], l1 = fusion[1];
        float mm = fmaxf(l0, l1);
        float e0 = __expf(l0 - mm), e1 = __expf(l1 - mm);
        float f0 = e0 / (e0 + e1), f1 = e1 / (e0 + e1);
        out[bid] = f0 * gscore[bid] + f1 * seg;
    }
}

extern "C" void kernel_launch(void* const* d_in, const int* in_sizes, int n_in,
                              void* d_out, int out_size, void* d_ws, size_t ws_size,
                              hipStream_t stream) {
    const float* sup = (const float*)d_in[0];    // [50,16,1024]
    const float* query = (const float*)d_in[1];  // [400,16,1024]
    const float* fusion = (const float*)d_in[2]; // [2]
    float* out = (float*)d_out;                  // [400,10]
    const int Q = in_sizes[1] / (T_LEN * D_DIM); // 400

    float* w = (float*)d_ws;
    size_t off = 0;
    float* proto = w + off;     off += (size_t)C_WAY * T_LEN * D_DIM;
    float* qcond = w + off;     off += (size_t)Q * NW * D_DIM;
    float* scond = w + off;     off += (size_t)C_WAY * NW * D_DIM;
    float* pn_inv = w + off;    off += C_WAY * T_LEN;
    float* qrow_inv = w + off;  off += (size_t)Q * T_LEN;
    float* gscore = w + off;    off += (size_t)Q * C_WAY;
    float* Gsup = w + off;      off += C_WAY * NW * 40 * 40;
    float* Gq = w + off;        off += (size_t)Q * NW * 64;
    float* SIM = w + off;       off += (size_t)Q * T_LEN * C_WAY * T_LEN;
    float* Sraw = w + off;      off += (size_t)Q * NW * C_WAY * NW * 40;
    float* Qraw = w + off;      off += (size_t)Q * NW * SEG_L * C_WAY * NW;
    int* map_cls = (int*)(w + off);  off += C_WAY * NW * 40;
    int* map_qseg = (int*)(w + off); off += (size_t)Q * NW * SEG_L;
    (void)ws_size; (void)n_in; (void)out_size;

    // precompute
    k_rowmaps<<<cdiv(Q * NW * SEG_L, 256), 256, 0, stream>>>(map_cls, map_qseg, Q);
    k_proto<<<C_WAY * T_LEN, 256, 0, stream>>>(sup, proto, pn_inv);
    k_rowinv<<<Q * T_LEN / 4, 256, 0, stream>>>(query, qrow_inv, Q * T_LEN);
    k_qcond<<<Q * NW, 256, 0, stream>>>(query, qcond);
    k_supcond<<<C_WAY * NW, 256, 0, stream>>>(sup, scond);

    // SIM = query · protoᵀ  [Q*16, 160]
    {
        dim3 g(cdiv(Q * T_LEN, 64), cdiv(C_WAY * T_LEN, 64), 1);
        gemm_bt<<<g, 256, 0, stream>>>(query, proto, SIM, Q * T_LEN, C_WAY * T_LEN, D_DIM,
                                       nullptr, 0, nullptr, 0, 0);
    }
    // S_raw = qcond · cls_supᵀ  [Q*3, 1200]  (cls_sup = support rows via map)
    {
        dim3 g(cdiv(Q * NW, 64), cdiv(C_WAY * NW * 40, 64), 1);
        gemm_bt<<<g, 256, 0, stream>>>(qcond, sup, Sraw, Q * NW, C_WAY * NW * 40, D_DIM,
                                       nullptr, 0, map_cls, 0, 0);
    }
    // Q_raw = q_seg · scondᵀ  [Q*24, 30]  (q_seg = query rows via map)
    {
        dim3 g(cdiv(Q * NW * SEG_L, 64), cdiv(C_WAY * NW, 64), 1);
        gemm_bt<<<g, 256, 0, stream>>>(query, scond, Qraw, Q * NW * SEG_L, C_WAY * NW, D_DIM,
                                       map_qseg, 0, nullptr, 0, 0);
    }
    // G_sup[b] = cls_sup[b] · cls_sup[b]ᵀ, b over 30 (c,w), 40×40 each
    {
        dim3 g(1, 1, C_WAY * NW);
        gemm_bt<<<g, 256, 0, stream>>>(sup, sup, Gsup, 40, 40, D_DIM,
                                       map_cls, 40, map_cls, 40, 1600);
    }
    k_gq<<<Q * NW, 64, 0, stream>>>(query, Gq);
    k_greduce<<<Q, 256, 0, stream>>>(SIM, qrow_inv, pn_inv, gscore);
    k_final<<<Q * C_WAY, 64, 0, stream>>>(Sraw, Qraw, Gsup, Gq, gscore, fusion, out);
}